// Round 5
// baseline (15100.652 us; speedup 1.0000x reference)
//
#include <hip/hip_runtime.h>

// QMogrifierStack: 2-layer mogrifier LSTM, B=64 S=512 IN=512 H=1024.
// Persistent cooperative kernel: 256 blocks (1/CU), blocks 0-127 = layer 0,
// 128-255 = layer 1, pipelined (layer1 one step behind layer0).
// R5: symmetric counter-ring grid barrier (1 atomicAdd + self-poll w/ sleep,
// no master relay), LDS pitch 1032 (proven bank-conflict floor), phase-1
// split by CHAIN (no LDS reduction), phase-2 split-K with 8KB reduction.
// Cross-block data: WT stores (sc0 sc1) + cached reads + one buffer_inv per
// block per barrier (L2 never dirty, so inv loses nothing).

typedef __attribute__((ext_vector_type(8))) short short8;
typedef __attribute__((ext_vector_type(4))) float f32x4;

constexpr int B_ = 64, S_ = 512, IN_ = 512, H_ = 1024;
constexpr int NBLK = 256, NTHR = 512;
constexpr int BH = B_ * H_;
constexpr int WP = 1032;              // LDS row pitch (shorts): 2064B = 16.125*128

__device__ __forceinline__ unsigned short f2bf(float f) {
  unsigned u = __builtin_bit_cast(unsigned, f);
  u += 0x7FFFu + ((u >> 16) & 1u);
  return (unsigned short)(u >> 16);
}
__device__ __forceinline__ float bf2f(unsigned short h) {
  unsigned u = ((unsigned)h) << 16;
  return __builtin_bit_cast(float, u);
}
__device__ __forceinline__ float sigm(float x) { return 1.f / (1.f + __expf(-x)); }
__device__ __forceinline__ float tanh_(float x) {
  float e = __expf(2.f * x);
  return 1.f - 2.f / (e + 1.f);
}

// Write-through stores (L2 stays clean; visible at coherence point after
// vmcnt(0), so barrier-exit buffer_inv never discards data).
__device__ __forceinline__ void store_short_wt(unsigned short* p, unsigned short v) {
  unsigned w = v;
  asm volatile("global_store_short %0, %1, off sc0 sc1" :: "v"(p), "v"(w) : "memory");
}
__device__ __forceinline__ void store_float_wt(float* p, float v) {
  asm volatile("global_store_dword %0, %1, off sc0 sc1" :: "v"(p), "v"(v) : "memory");
}

// Symmetric counter-ring barrier: one fresh pre-zeroed counter per instance.
// arrive: drain WT stores -> syncthreads -> tid0 no-return atomicAdd
// wait:   tid0 polls the counter (relaxed agent load) with s_sleep backoff
// exit:   tid0 buffer_inv sc1 (refresh cross-block lines) -> syncthreads
__device__ __forceinline__ void gridbar(int* ctrs, int eidx) {
  asm volatile("s_waitcnt vmcnt(0)" ::: "memory");
  __syncthreads();
  if (threadIdx.x == 0) {
    int* c = &ctrs[eidx * 16];
    __hip_atomic_fetch_add(c, 1, __ATOMIC_RELAXED, __HIP_MEMORY_SCOPE_AGENT);
    while (__hip_atomic_load(c, __ATOMIC_RELAXED, __HIP_MEMORY_SCOPE_AGENT) < NBLK)
      __builtin_amdgcn_s_sleep(1);
    asm volatile("buffer_inv sc1\n\ts_waitcnt vmcnt(0)" ::: "memory");
  }
  __syncthreads();
}

__global__ __launch_bounds__(NTHR, 1) void qmog_kernel(
    const float* __restrict__ seq, const float* __restrict__ dseq,
    const float* __restrict__ lqseq,
    const float* __restrict__ modW0, const float* __restrict__ modb0,
    const float* __restrict__ Wih0, const float* __restrict__ Whh0,
    const float* __restrict__ bih0, const float* __restrict__ bhh0,
    const float* __restrict__ modW1, const float* __restrict__ modb1,
    const float* __restrict__ Wih1, const float* __restrict__ Whh1,
    const float* __restrict__ bih1, const float* __restrict__ bhh1,
    float* __restrict__ dout, int* __restrict__ ctrs,
    unsigned short* __restrict__ h0r, unsigned short* __restrict__ h1r,
    unsigned short* __restrict__ u0, unsigned short* __restrict__ u1) {
  __shared__ unsigned short Wih_s[32 * WP];   // 66048 B
  __shared__ unsigned short Whh_s[32 * WP];   // 66048 B
  __shared__ unsigned short modW_s[8 * WP];   // 16512 B
  __shared__ float red_s[4][8][64];           // 8192 B (phase-2 split-K)
  __shared__ float bias_s[32];
  __shared__ float wd_s[8], wl_s[8], mb_s[8];

  const int bid = blockIdx.x, tid = threadIdx.x;
  const int layer = bid >> 7;
  const int slice = bid & 127;
  const int wave = tid >> 6, lane = tid & 63;
  const int wgrp = wave >> 2;         // 0: Whh chains / K-half0; 1: mod / K-half1
  const int mt = wave & 3;            // M-tile (16 batch rows)
  const int Kin = layer ? H_ : IN_;   // 1024 / 512
  const int KU = Kin / 32;            // 32 / 16 k-tiles (phase 2 total)
  const int MCB = layer ? 8 : 4;      // m-cols per block
  const int hc0 = slice * 8;
  const int mc0 = slice * MCB;
  const float* modW = layer ? modW1 : modW0;
  const float* modb = layer ? modb1 : modb0;
  const float* Wih  = layer ? Wih1 : Wih0;
  const float* Whh  = layer ? Whh1 : Whh0;
  const float* bih  = layer ? bih1 : bih0;
  const float* bhh  = layer ? bhh1 : bhh0;
  unsigned short* ubuf = layer ? u1 : u0;
  unsigned short* myring = layer ? h1r : h0r;

  // ---- stage weight slices f32->bf16 into LDS ----
  // LDS row r -> global gate row (r>>3)*H + hc0 + (r&7): [i0..7,f0..7,g0..7,o0..7]
  for (int idx = tid; idx < 32 * Kin; idx += NTHR) {
    int row = idx / Kin, k = idx - row * Kin;
    int grow = (row >> 3) * H_ + hc0 + (row & 7);
    Wih_s[row * WP + k] = f2bf(Wih[grow * Kin + k]);
  }
  for (int idx = tid; idx < 32 * H_; idx += NTHR) {
    int row = idx >> 10, k = idx & (H_ - 1);
    int grow = (row >> 3) * H_ + hc0 + (row & 7);
    Whh_s[row * WP + k] = f2bf(Whh[grow * H_ + k]);
  }
  for (int idx = tid; idx < MCB * H_; idx += NTHR) {
    int row = idx >> 10, k = idx & (H_ - 1);
    modW_s[row * WP + k] = f2bf(modW[(mc0 + row) * (H_ + 2) + k]);
  }
  if (tid < 32) {
    int grow = (tid >> 3) * H_ + hc0 + (tid & 7);
    bias_s[tid] = bih[grow] + bhh[grow];
  }
  if (tid < MCB) {
    wd_s[tid] = modW[(mc0 + tid) * (H_ + 2) + H_];
    wl_s[tid] = modW[(mc0 + tid) * (H_ + 2) + H_ + 1];
    mb_s[tid] = modb[mc0 + tid];
  }
  __syncthreads();

  float creg0 = 0.f, creg1 = 0.f;     // cell state (waves 0-3 only)
  const int c = lane & 15, kg = lane >> 4;
  const int cm = c & (MCB - 1);

  for (int s = 0; s <= S_; ++s) {
    const int t = layer ? (s - 1) : s;
    const bool active = (t >= 0) && (t < S_);

    // h@Whh^T totals, carried phase1 -> phase2 in waves 0-3 registers
    f32x4 pm0 = {0,0,0,0}, pm1 = {0,0,0,0};

    if (active) {
      // ---- phase 1, split by CHAIN (no LDS reduction) ----
      if (wgrp == 0) {
        // waves 0-3: p0/p1 = h@Whh^T (full K=1024), 4 interleaved chains
        if (t > 0) {
          f32x4 p0A = {0,0,0,0}, p0B = {0,0,0,0}, p1A = {0,0,0,0}, p1B = {0,0,0,0};
          const unsigned short* hrow =
              myring + ((t - 1) & 1) * BH + (mt * 16 + c) * H_;
          const unsigned short* w0b = Whh_s + c * WP;
          const unsigned short* w1b = Whh_s + (16 + c) * WP;
#pragma unroll 8
          for (int kk = 0; kk < 32; ++kk) {
            short8 ha = *(const short8*)(hrow + kk * 32 + kg * 8);
            short8 w0 = *(const short8*)(w0b + kk * 32 + kg * 8);
            short8 w1 = *(const short8*)(w1b + kk * 32 + kg * 8);
            if (kk & 1) {
              p0B = __builtin_amdgcn_mfma_f32_16x16x32_bf16(ha, w0, p0B, 0, 0, 0);
              p1B = __builtin_amdgcn_mfma_f32_16x16x32_bf16(ha, w1, p1B, 0, 0, 0);
            } else {
              p0A = __builtin_amdgcn_mfma_f32_16x16x32_bf16(ha, w0, p0A, 0, 0, 0);
              p1A = __builtin_amdgcn_mfma_f32_16x16x32_bf16(ha, w1, p1A, 0, 0, 0);
            }
          }
#pragma unroll
          for (int r = 0; r < 4; ++r) {
            pm0[r] = p0A[r] + p0B[r];
            pm1[r] = p1A[r] + p1B[r];
          }
        }
      } else {
        // waves 4-7: m = sigmoid(h@modW^T + d*wd + lq*wl + mb); u = m*x
        f32x4 mA = {0,0,0,0}, mB = {0,0,0,0};
        if (t > 0) {
          const unsigned short* hrow =
              myring + ((t - 1) & 1) * BH + (mt * 16 + c) * H_;
          const unsigned short* wm = modW_s + cm * WP;
#pragma unroll 8
          for (int kk = 0; kk < 32; ++kk) {
            short8 ha = *(const short8*)(hrow + kk * 32 + kg * 8);
            short8 bm = *(const short8*)(wm + kk * 32 + kg * 8);
            if (kk & 1)
              mB = __builtin_amdgcn_mfma_f32_16x16x32_bf16(ha, bm, mB, 0, 0, 0);
            else
              mA = __builtin_amdgcn_mfma_f32_16x16x32_bf16(ha, bm, mA, 0, 0, 0);
          }
        }
        if (c < MCB) {
          const float wd = wd_s[cm], wl = wl_s[cm], mb = mb_s[cm];
#pragma unroll
          for (int r = 0; r < 4; ++r) {
            int b_ = mt * 16 + kg * 4 + r;
            float dt = dseq[b_ * S_ + t];
            float lq = lqseq[b_ * S_ + t];
            float mval = sigm(mA[r] + mB[r] + dt * wd + lq * wl + mb);
            float xv = layer ? bf2f(h0r[(t & 1) * BH + b_ * H_ + mc0 + c])
                             : seq[(b_ * S_ + t) * IN_ + mc0 + c];
            store_short_wt(&ubuf[b_ * Kin + mc0 + c], f2bf(mval * xv));
          }
        }
      }
    }
    gridbar(ctrs, s * 2);

    if (active) {
      // ---- phase 2: u@Wih^T split-K over wave groups; combine + cell ----
      f32x4 g0A = {0,0,0,0}, g0B = {0,0,0,0}, g1A = {0,0,0,0}, g1B = {0,0,0,0};
      const int ku2 = KU >> 1;        // 8 (L0) / 16 (L1) k-tiles per wave
      const unsigned short* urow = ubuf + (mt * 16 + c) * Kin + wgrp * (ku2 * 32);
      const unsigned short* v0b = Wih_s + c * WP + wgrp * (ku2 * 32);
      const unsigned short* v1b = Wih_s + (16 + c) * WP + wgrp * (ku2 * 32);
#pragma unroll
      for (int kk = 0; kk < 16; ++kk) {
        if (kk < ku2) {
          short8 au = *(const short8*)(urow + kk * 32 + kg * 8);
          short8 v0 = *(const short8*)(v0b + kk * 32 + kg * 8);
          short8 v1 = *(const short8*)(v1b + kk * 32 + kg * 8);
          if (kk & 1) {
            g0B = __builtin_amdgcn_mfma_f32_16x16x32_bf16(au, v0, g0B, 0, 0, 0);
            g1B = __builtin_amdgcn_mfma_f32_16x16x32_bf16(au, v1, g1B, 0, 0, 0);
          } else {
            g0A = __builtin_amdgcn_mfma_f32_16x16x32_bf16(au, v0, g0A, 0, 0, 0);
            g1A = __builtin_amdgcn_mfma_f32_16x16x32_bf16(au, v1, g1A, 0, 0, 0);
          }
        }
      }
      if (wgrp) {
#pragma unroll
        for (int r = 0; r < 4; ++r) {
          red_s[mt][r][lane] = g0A[r] + g0B[r];
          red_s[mt][4 + r][lane] = g1A[r] + g1B[r];
        }
      }
      __syncthreads();
      if (!wgrp) {
        const float bia0 = bias_s[c], bia1 = bias_s[16 + c];
        f32x4 g0, g1, s0, s1;
#pragma unroll
        for (int r = 0; r < 4; ++r) {
          g0[r] = g0A[r] + g0B[r] + red_s[mt][r][lane] + pm0[r] + bia0;
          g1[r] = g1A[r] + g1B[r] + red_s[mt][4 + r][lane] + pm1[r] + bia1;
        }
#pragma unroll
        for (int r = 0; r < 4; ++r) {
          s0[r] = __shfl_xor(g0[r], 8);
          s1[r] = __shfl_xor(g1[r], 8);
        }
        // Lane c<8 holds i (tile0) / g (tile1); c>=8 holds f / o. After xor-8
        // all four present; low lanes take rows 0,1, high lanes rows 2,3.
        const bool low = c < 8;
        const int hc = hc0 + (c & 7);
        const int rbase = low ? 0 : 2;
#pragma unroll
        for (int j = 0; j < 2; ++j) {
          const int rr = rbase + j;
          float iv = low ? g0[rr] : s0[rr];
          float fv = low ? s0[rr] : g0[rr];
          float gv = low ? g1[rr] : s1[rr];
          float ov = low ? s1[rr] : g1[rr];
          float cold = j ? creg1 : creg0;
          float cn = sigm(fv) * cold + sigm(iv) * tanh_(gv);
          float hn = sigm(ov) * tanh_(cn);
          if (j) creg1 = cn; else creg0 = cn;
          int b_ = mt * 16 + kg * 4 + rr;
          store_short_wt(&myring[(t & 1) * BH + b_ * H_ + hc], f2bf(hn));
          if (layer) {
            store_float_wt(&dout[(b_ * S_ + t) * H_ + hc], hn);
            if (t == S_ - 1) store_float_wt(&dout[B_ * S_ * H_ + b_ * H_ + hc], hn);
          }
        }
      }
    }
    gridbar(ctrs, s * 2 + 1);
  }
}

extern "C" void kernel_launch(void* const* d_in, const int* in_sizes, int n_in,
                              void* d_out, int out_size, void* d_ws,
                              size_t ws_size, hipStream_t stream) {
  char* w = (char*)d_ws;
  int* ctrs = (int*)w;                                       // 66,560 B ring
  unsigned short* h0r = (unsigned short*)(w + 66560);        // 262,144 B
  unsigned short* h1r = (unsigned short*)(w + 66560 + 262144);
  unsigned short* u0 = (unsigned short*)(w + 66560 + 2 * 262144);           // 64 KB
  unsigned short* u1 = (unsigned short*)(w + 66560 + 2 * 262144 + 65536);   // 128 KB

  hipMemsetAsync(ctrs, 0, 66560, stream);   // fresh counters each launch

  qmog_kernel<<<NBLK, NTHR, 0, stream>>>(
      (const float*)d_in[0], (const float*)d_in[1], (const float*)d_in[2],
      (const float*)d_in[3], (const float*)d_in[4], (const float*)d_in[5],
      (const float*)d_in[6], (const float*)d_in[7], (const float*)d_in[8],
      (const float*)d_in[9], (const float*)d_in[10], (const float*)d_in[11],
      (const float*)d_in[12], (const float*)d_in[13], (const float*)d_in[14],
      (float*)d_out, ctrs, h0r, h1r, u0, u1);
}

// Round 6
// 10657.108 us; speedup vs baseline: 1.4170x; 1.4170x over previous
//
#include <hip/hip_runtime.h>

// QMogrifierStack: 2-layer mogrifier LSTM, B=64 S=512 IN=512 H=1024.
// Persistent cooperative kernel: 256 blocks (1/CU), blocks 0-127 = layer 0,
// 128-255 = layer 1, pipelined (layer1 one step behind layer0).
// R6: master-worker relay barrier (R4, proven) with role-specialized waves:
//   phase 1: waves 0-3 = Whh GEMM (long); waves 4-7 = mod GEMM + u store,
//   then arrive (LDS fan-in -> wave4 posts flag). Block0 wave5 = dedicated
//   master poller; wave6 polls go + buffer_inv. Barrier-1 latency is hidden
//   behind the Whh chain. Barrier 2 = plain relay.
// LDS pitch 1032 (bank-conflict floor). Cross-block data: WT stores (sc0 sc1)
// + cached reads + one buffer_inv per block per barrier.

typedef __attribute__((ext_vector_type(8))) short short8;
typedef __attribute__((ext_vector_type(4))) float f32x4;

constexpr int B_ = 64, S_ = 512, IN_ = 512, H_ = 1024;
constexpr int NBLK = 256, NTHR = 512;
constexpr int BH = B_ * H_;
constexpr int WP = 1032;              // LDS row pitch (shorts)

__device__ __forceinline__ unsigned short f2bf(float f) {
  unsigned u = __builtin_bit_cast(unsigned, f);
  u += 0x7FFFu + ((u >> 16) & 1u);
  return (unsigned short)(u >> 16);
}
__device__ __forceinline__ float bf2f(unsigned short h) {
  unsigned u = ((unsigned)h) << 16;
  return __builtin_bit_cast(float, u);
}
__device__ __forceinline__ float sigm(float x) { return 1.f / (1.f + __expf(-x)); }
__device__ __forceinline__ float tanh_(float x) {
  float e = __expf(2.f * x);
  return 1.f - 2.f / (e + 1.f);
}

// Write-through stores (L2 stays clean; at coherence point after vmcnt(0)).
__device__ __forceinline__ void store_short_wt(unsigned short* p, unsigned short v) {
  unsigned w = v;
  asm volatile("global_store_short %0, %1, off sc0 sc1" :: "v"(p), "v"(w) : "memory");
}
__device__ __forceinline__ void store_float_wt(float* p, float v) {
  asm volatile("global_store_dword %0, %1, off sc0 sc1" :: "v"(p), "v"(v) : "memory");
}

__device__ __forceinline__ int aload(int* p) {
  return __hip_atomic_load(p, __ATOMIC_RELAXED, __HIP_MEMORY_SCOPE_AGENT);
}
__device__ __forceinline__ void astore(int* p, int v) {
  __hip_atomic_store(p, v, __ATOMIC_RELAXED, __HIP_MEMORY_SCOPE_AGENT);
}

// Master poll: 64 lanes x 4 flags; then lanes 0-7 publish 8 go slots.
__device__ __forceinline__ void master_relay(int* arr, int* go, int ep, int lane) {
  bool ok;
  do {
    ok = true;
#pragma unroll
    for (int i = 0; i < 4; ++i) ok &= (aload(&arr[lane + i * 64]) >= ep);
  } while (!__all(ok));
  if (lane < 8) astore(&go[lane << 5], ep);
}

__global__ __launch_bounds__(NTHR, 1) void qmog_kernel(
    const float* __restrict__ seq, const float* __restrict__ dseq,
    const float* __restrict__ lqseq,
    const float* __restrict__ modW0, const float* __restrict__ modb0,
    const float* __restrict__ Wih0, const float* __restrict__ Whh0,
    const float* __restrict__ bih0, const float* __restrict__ bhh0,
    const float* __restrict__ modW1, const float* __restrict__ modb1,
    const float* __restrict__ Wih1, const float* __restrict__ Whh1,
    const float* __restrict__ bih1, const float* __restrict__ bhh1,
    float* __restrict__ dout, int* __restrict__ flags,
    unsigned short* __restrict__ h0r, unsigned short* __restrict__ h1r,
    unsigned short* __restrict__ u0, unsigned short* __restrict__ u1) {
  __shared__ unsigned short Wih_s[32 * WP];   // 66048 B
  __shared__ unsigned short Whh_s[32 * WP];   // 66048 B
  __shared__ unsigned short modW_s[8 * WP];   // 16512 B
  __shared__ float red_s[4][8][64];           // 8192 B (phase-2 split-K)
  __shared__ float bias_s[32];
  __shared__ float wd_s[8], wl_s[8], mb_s[8];
  __shared__ int p1cnt;

  const int bid = blockIdx.x, tid = threadIdx.x;
  const int layer = bid >> 7;
  const int slice = bid & 127;
  const int wave = tid >> 6, lane = tid & 63;
  const int wgrp = wave >> 2;         // 0: Whh+cell waves; 1: mod/arrive waves
  const int mt = wave & 3;            // M-tile (16 batch rows)
  const int Kin = layer ? H_ : IN_;   // 1024 / 512
  const int KU = Kin / 32;            // 32 / 16 k-tiles (phase 2 total)
  const int MCB = layer ? 8 : 4;      // m-cols per block
  const int hc0 = slice * 8;
  const int mc0 = slice * MCB;
  const float* modW = layer ? modW1 : modW0;
  const float* modb = layer ? modb1 : modb0;
  const float* Wih  = layer ? Wih1 : Wih0;
  const float* Whh  = layer ? Whh1 : Whh0;
  const float* bih  = layer ? bih1 : bih0;
  const float* bhh  = layer ? bhh1 : bhh0;
  unsigned short* ubuf = layer ? u1 : u0;
  unsigned short* myring = layer ? h1r : h0r;

  int* arr1 = flags;        // [256]
  int* go1  = flags + 256;  // 8 slots, stride 32
  int* arr2 = flags + 512;
  int* go2  = flags + 768;

  // ---- stage weight slices f32->bf16 into LDS ----
  // LDS row r -> global gate row (r>>3)*H + hc0 + (r&7): [i0..7,f0..7,g0..7,o0..7]
  for (int idx = tid; idx < 32 * Kin; idx += NTHR) {
    int row = idx / Kin, k = idx - row * Kin;
    int grow = (row >> 3) * H_ + hc0 + (row & 7);
    Wih_s[row * WP + k] = f2bf(Wih[grow * Kin + k]);
  }
  for (int idx = tid; idx < 32 * H_; idx += NTHR) {
    int row = idx >> 10, k = idx & (H_ - 1);
    int grow = (row >> 3) * H_ + hc0 + (row & 7);
    Whh_s[row * WP + k] = f2bf(Whh[grow * H_ + k]);
  }
  for (int idx = tid; idx < MCB * H_; idx += NTHR) {
    int row = idx >> 10, k = idx & (H_ - 1);
    modW_s[row * WP + k] = f2bf(modW[(mc0 + row) * (H_ + 2) + k]);
  }
  if (tid < 32) {
    int grow = (tid >> 3) * H_ + hc0 + (tid & 7);
    bias_s[tid] = bih[grow] + bhh[grow];
  }
  if (tid < MCB) {
    wd_s[tid] = modW[(mc0 + tid) * (H_ + 2) + H_];
    wl_s[tid] = modW[(mc0 + tid) * (H_ + 2) + H_ + 1];
    mb_s[tid] = modb[mc0 + tid];
  }
  if (tid == 0) p1cnt = 0;
  __syncthreads();

  float creg0 = 0.f, creg1 = 0.f;     // cell state (waves 0-3 only)
  const int c = lane & 15, kg = lane >> 4;
  const int cm = c & (MCB - 1);

  for (int s = 0; s <= S_; ++s) {
    const int t = layer ? (s - 1) : s;
    const bool active = (t >= 0) && (t < S_);
    const int ep = s + 1;

    // h@Whh^T totals, carried phase1 -> phase2 in waves 0-3 registers
    f32x4 pm0 = {0,0,0,0}, pm1 = {0,0,0,0};

    // ---- phase 1 compute ----
    if (active) {
      if (wgrp == 0) {
        // waves 0-3: p0/p1 = h@Whh^T (full K), 4 interleaved chains (long)
        if (t > 0) {
          f32x4 p0A = {0,0,0,0}, p0B = {0,0,0,0}, p1A = {0,0,0,0}, p1B = {0,0,0,0};
          const unsigned short* hrow =
              myring + ((t - 1) & 1) * BH + (mt * 16 + c) * H_;
          const unsigned short* w0b = Whh_s + c * WP;
          const unsigned short* w1b = Whh_s + (16 + c) * WP;
#pragma unroll 8
          for (int kk = 0; kk < 32; ++kk) {
            short8 ha = *(const short8*)(hrow + kk * 32 + kg * 8);
            short8 w0 = *(const short8*)(w0b + kk * 32 + kg * 8);
            short8 w1 = *(const short8*)(w1b + kk * 32 + kg * 8);
            if (kk & 1) {
              p0B = __builtin_amdgcn_mfma_f32_16x16x32_bf16(ha, w0, p0B, 0, 0, 0);
              p1B = __builtin_amdgcn_mfma_f32_16x16x32_bf16(ha, w1, p1B, 0, 0, 0);
            } else {
              p0A = __builtin_amdgcn_mfma_f32_16x16x32_bf16(ha, w0, p0A, 0, 0, 0);
              p1A = __builtin_amdgcn_mfma_f32_16x16x32_bf16(ha, w1, p1A, 0, 0, 0);
            }
          }
#pragma unroll
          for (int r = 0; r < 4; ++r) {
            pm0[r] = p0A[r] + p0B[r];
            pm1[r] = p1A[r] + p1B[r];
          }
        }
      } else {
        // waves 4-7: m = sigmoid(h@modW^T + d*wd + lq*wl + mb); u = m*x (short)
        f32x4 mA = {0,0,0,0}, mB = {0,0,0,0};
        if (t > 0) {
          const unsigned short* hrow =
              myring + ((t - 1) & 1) * BH + (mt * 16 + c) * H_;
          const unsigned short* wm = modW_s + cm * WP;
#pragma unroll 8
          for (int kk = 0; kk < 32; ++kk) {
            short8 ha = *(const short8*)(hrow + kk * 32 + kg * 8);
            short8 bm = *(const short8*)(wm + kk * 32 + kg * 8);
            if (kk & 1)
              mB = __builtin_amdgcn_mfma_f32_16x16x32_bf16(ha, bm, mB, 0, 0, 0);
            else
              mA = __builtin_amdgcn_mfma_f32_16x16x32_bf16(ha, bm, mA, 0, 0, 0);
          }
        }
        if (c < MCB) {
          const float wd = wd_s[cm], wl = wl_s[cm], mb = mb_s[cm];
#pragma unroll
          for (int r = 0; r < 4; ++r) {
            int b_ = mt * 16 + kg * 4 + r;
            float dt = dseq[b_ * S_ + t];
            float lq = lqseq[b_ * S_ + t];
            float mval = sigm(mA[r] + mB[r] + dt * wd + lq * wl + mb);
            float xv = layer ? bf2f(h0r[(t & 1) * BH + b_ * H_ + mc0 + c])
                             : seq[(b_ * S_ + t) * IN_ + mc0 + c];
            store_short_wt(&ubuf[b_ * Kin + mc0 + c], f2bf(mval * xv));
          }
        }
      }
    }

    // ---- barrier 1 (relay overlapped with waves 0-3's Whh chain) ----
    if (wgrp) {
      asm volatile("s_waitcnt vmcnt(0)" ::: "memory");  // u stores @ CP
      if (lane == 0)
        __hip_atomic_fetch_add(&p1cnt, 1, __ATOMIC_RELAXED,
                               __HIP_MEMORY_SCOPE_WORKGROUP);
      if (wave == 4 && lane == 0) {
        while (__hip_atomic_load(&p1cnt, __ATOMIC_RELAXED,
                                 __HIP_MEMORY_SCOPE_WORKGROUP) < 4 * ep) {}
        astore(&arr1[bid], ep);      // all 4 mod-waves drained -> arrive
      }
      if (bid == 0 && wave == 5) master_relay(arr1, go1, ep, lane);
      if (wave == 6 && lane == 0) {
        while (aload(&go1[(bid & 7) << 5]) < ep) {}
        asm volatile("buffer_inv sc1\n\ts_waitcnt vmcnt(0)" ::: "memory");
      }
    }
    __syncthreads();   // phase 2 starts only after go + inv

    // ---- phase 2: u@Wih^T split-K; combine + cell in waves 0-3 ----
    if (active) {
      f32x4 g0A = {0,0,0,0}, g0B = {0,0,0,0}, g1A = {0,0,0,0}, g1B = {0,0,0,0};
      const int ku2 = KU >> 1;        // 8 (L0) / 16 (L1) k-tiles per wave
      const unsigned short* urow = ubuf + (mt * 16 + c) * Kin + wgrp * (ku2 * 32);
      const unsigned short* v0b = Wih_s + c * WP + wgrp * (ku2 * 32);
      const unsigned short* v1b = Wih_s + (16 + c) * WP + wgrp * (ku2 * 32);
#pragma unroll
      for (int kk = 0; kk < 16; ++kk) {
        if (kk < ku2) {
          short8 au = *(const short8*)(urow + kk * 32 + kg * 8);
          short8 v0 = *(const short8*)(v0b + kk * 32 + kg * 8);
          short8 v1 = *(const short8*)(v1b + kk * 32 + kg * 8);
          if (kk & 1) {
            g0B = __builtin_amdgcn_mfma_f32_16x16x32_bf16(au, v0, g0B, 0, 0, 0);
            g1B = __builtin_amdgcn_mfma_f32_16x16x32_bf16(au, v1, g1B, 0, 0, 0);
          } else {
            g0A = __builtin_amdgcn_mfma_f32_16x16x32_bf16(au, v0, g0A, 0, 0, 0);
            g1A = __builtin_amdgcn_mfma_f32_16x16x32_bf16(au, v1, g1A, 0, 0, 0);
          }
        }
      }
      if (wgrp) {
#pragma unroll
        for (int r = 0; r < 4; ++r) {
          red_s[mt][r][lane] = g0A[r] + g0B[r];
          red_s[mt][4 + r][lane] = g1A[r] + g1B[r];
        }
      }
      __syncthreads();               // block-uniform branch: legal
      if (!wgrp) {
        const float bia0 = bias_s[c], bia1 = bias_s[16 + c];
        f32x4 g0, g1, s0, s1;
#pragma unroll
        for (int r = 0; r < 4; ++r) {
          g0[r] = g0A[r] + g0B[r] + red_s[mt][r][lane] + pm0[r] + bia0;
          g1[r] = g1A[r] + g1B[r] + red_s[mt][4 + r][lane] + pm1[r] + bia1;
        }
#pragma unroll
        for (int r = 0; r < 4; ++r) {
          s0[r] = __shfl_xor(g0[r], 8);
          s1[r] = __shfl_xor(g1[r], 8);
        }
        // Lane c<8 holds i (tile0) / g (tile1); c>=8 holds f / o. After xor-8
        // all four present; low lanes take rows 0,1, high lanes rows 2,3.
        const bool low = c < 8;
        const int hc = hc0 + (c & 7);
        const int rbase = low ? 0 : 2;
#pragma unroll
        for (int j = 0; j < 2; ++j) {
          const int rr = rbase + j;
          float iv = low ? g0[rr] : s0[rr];
          float fv = low ? s0[rr] : g0[rr];
          float gv = low ? g1[rr] : s1[rr];
          float ov = low ? s1[rr] : g1[rr];
          float cold = j ? creg1 : creg0;
          float cn = sigm(fv) * cold + sigm(iv) * tanh_(gv);
          float hn = sigm(ov) * tanh_(cn);
          if (j) creg1 = cn; else creg0 = cn;
          int b_ = mt * 16 + kg * 4 + rr;
          store_short_wt(&myring[(t & 1) * BH + b_ * H_ + hc], f2bf(hn));
          if (layer) {
            store_float_wt(&dout[(b_ * S_ + t) * H_ + hc], hn);
            if (t == S_ - 1) store_float_wt(&dout[B_ * S_ * H_ + b_ * H_ + hc], hn);
          }
        }
      }
    }

    // ---- barrier 2 (plain relay; h_t must be globally visible) ----
    if (!wgrp) asm volatile("s_waitcnt vmcnt(0)" ::: "memory");  // h stores @ CP
    __syncthreads();
    if (wave == 4 && lane == 0) astore(&arr2[bid], ep);
    if (bid == 0 && wave == 5) master_relay(arr2, go2, ep, lane);
    if (wave == 6 && lane == 0) {
      while (aload(&go2[(bid & 7) << 5]) < ep) {}
      asm volatile("buffer_inv sc1\n\ts_waitcnt vmcnt(0)" ::: "memory");
    }
    __syncthreads();
  }
}

extern "C" void kernel_launch(void* const* d_in, const int* in_sizes, int n_in,
                              void* d_out, int out_size, void* d_ws,
                              size_t ws_size, hipStream_t stream) {
  char* w = (char*)d_ws;
  int* flags = (int*)w;                                      // 4 KB used
  unsigned short* h0r = (unsigned short*)(w + 16384);        // 262,144 B
  unsigned short* h1r = (unsigned short*)(w + 16384 + 262144);
  unsigned short* u0 = (unsigned short*)(w + 16384 + 2 * 262144);           // 64 KB
  unsigned short* u1 = (unsigned short*)(w + 16384 + 2 * 262144 + 65536);   // 128 KB

  hipMemsetAsync(flags, 0, 16384, stream);   // fresh epochs each launch

  qmog_kernel<<<NBLK, NTHR, 0, stream>>>(
      (const float*)d_in[0], (const float*)d_in[1], (const float*)d_in[2],
      (const float*)d_in[3], (const float*)d_in[4], (const float*)d_in[5],
      (const float*)d_in[6], (const float*)d_in[7], (const float*)d_in[8],
      (const float*)d_in[9], (const float*)d_in[10], (const float*)d_in[11],
      (const float*)d_in[12], (const float*)d_in[13], (const float*)d_in[14],
      (float*)d_out, flags, h0r, h1r, u0, u1);
}